// Round 8
// baseline (150.017 us; speedup 1.0000x reference)
//
#include <hip/hip_runtime.h>
#include <math.h>

// CLUB_NCE: N=512, D=400, H=400.  Two dispatches total.
// K1 : hidden GEMMs, full-K (no partials). 848 blocks x 256 thr (3.3 waves/SIMD).
//      Lane-dim operand staged in LDS (two 200-k chunks, acc in regs),
//      2 wave-uniform scalar rows per wave thread (s_load path).
//      mat0 (blocks 0..399):  hxT8[h/8][j][h%8] = x @ W1x^T   (lane = j)
//      mat1 (blocks 400..847): hyb[n][h] = y @ W1y^T + b1     (lane = h)
//      Block 0 also zeroes K2's completion counter.
// K2 : pair scores, 512 blocks x 256 thr. Wave = 4 i-rows x 64 j x 200 h-half;
//      half-pairs combine via LDS; fused softplus + per-row fp64 reduction;
//      LAST block (device atomic counter) does the fp64 logsumexp finish.

#define NSAMP 512
#define DIM 400
#define HID 400

// ---------------- K1 ----------------
__global__ __launch_bounds__(256) void club_gemm_kernel(
    const float* __restrict__ X, const float* __restrict__ Y,
    const float* __restrict__ W1, const float* __restrict__ b1,
    float* __restrict__ hxT8, float* __restrict__ hyb,
    unsigned int* __restrict__ counter)
{
    __shared__ __align__(16) float Ls[64 * 204];   // 52224 B -> 3 blocks/CU
    const int t    = threadIdx.x;
    const int lane = t & 63;
    const int wave = __builtin_amdgcn_readfirstlane(t >> 6);
    const int b    = blockIdx.x;
    if (b == 0 && t == 0) *counter = 0u;           // for K2's last-block pattern

    const float* __restrict__ Lbase;   // lane-dim matrix (LDS-staged)
    const float* __restrict__ Sbase;   // scalar-dim matrix (uniform s_load path)
    int Lstride, Lcol0, Lrow0, Lrowmax, Sstride, sr0;
    int mat;

    if (b < 400) {                    // mat0: hx
        mat = 0;
        const int bx = b & 7, by = b >> 3;          // j-tile, h-oct (0..49)
        Lbase = X;  Lstride = DIM;     Lcol0 = 0;   Lrow0 = bx * 64; Lrowmax = NSAMP - 1;
        Sbase = W1; Sstride = 2 * DIM;
        sr0 = by * 8 + wave * 2;                    // h rows (<= 399)
    } else {                          // mat1: hy (+b1)
        mat = 1;
        const int bb = b - 400;
        const int bx = bb & 63, by = bb >> 6;       // n-group, h-tile (0..6)
        Lbase = W1; Lstride = 2 * DIM; Lcol0 = DIM; Lrow0 = by * 64; Lrowmax = HID - 1;
        Sbase = Y;  Sstride = DIM;
        sr0 = bx * 8 + wave * 2;                    // n rows (<= 511)
    }

    float acc0 = 0.f, acc1 = 0.f;                   // 2 scalar rows x lane

    for (int kc = 0; kc < DIM; kc += 200) {
        __syncthreads();
        // stage lane-dim tile: 64 rows x 200 k -> Ls, coalesced float4
        for (int idx = t; idx < 3200; idx += 256) {
            int row = idx / 50, q = idx % 50;
            int r = Lrow0 + row; if (r > Lrowmax) r = Lrowmax;
            float4 v = *(const float4*)(Lbase + (size_t)r * Lstride + Lcol0 + kc + 4 * q);
            *(float4*)(Ls + row * 204 + 4 * q) = v;
        }
        __syncthreads();
        const float* __restrict__ w0p = Sbase + (size_t)sr0 * Sstride + kc;        // uniform
        const float* __restrict__ w1p = Sbase + (size_t)(sr0 + 1) * Sstride + kc;  // uniform
#pragma unroll 2
        for (int k4 = 0; k4 < 50; k4++) {
            float4 xv = *(const float4*)(Ls + lane * 204 + 4 * k4);
            float4 wa = *(const float4*)(w0p + 4 * k4);
            float4 wb = *(const float4*)(w1p + 4 * k4);
            acc0 = fmaf(xv.x, wa.x, acc0);
            acc0 = fmaf(xv.y, wa.y, acc0);
            acc0 = fmaf(xv.z, wa.z, acc0);
            acc0 = fmaf(xv.w, wa.w, acc0);
            acc1 = fmaf(xv.x, wb.x, acc1);
            acc1 = fmaf(xv.y, wb.y, acc1);
            acc1 = fmaf(xv.z, wb.z, acc1);
            acc1 = fmaf(xv.w, wb.w, acc1);
        }
    }

    if (mat == 0) {
        // hxT8[oct g][j][h&7]; rows sr0, sr0+1 are consecutive h -> float2 store
        const int g = sr0 >> 3;                    // = by
        const int j = Lrow0 + lane;
        *(float2*)(hxT8 + ((size_t)g * NSAMP + j) * 8 + (sr0 & 7)) =
            make_float2(acc0, acc1);
    } else {
        const int h = Lrow0 + lane;
        if (h < HID) {
            float bv = b1[h];
            hyb[(size_t)sr0 * HID + h]       = acc0 + bv;
            hyb[(size_t)(sr0 + 1) * HID + h] = acc1 + bv;
        }
    }
}

// ---------------- K2: pair scores + fused final ----------------
// grid (8 jx, 64 ig), block 256 (4 waves). wave = (i-group grp, h-half):
//   grp = wave>>1 -> i = ig*8 + grp*4 + c (c=0..3); half = wave&1 -> h in [half*200, +200)
__global__ __launch_bounds__(256) void club_pair_kernel(
    const float* __restrict__ hxT8, const float* __restrict__ hyb,
    const float* __restrict__ W2, const float* __restrict__ b2,
    double* __restrict__ expsum, double* __restrict__ tsum,
    double* __restrict__ diagT, unsigned int* __restrict__ counter,
    float* __restrict__ out)
{
    __shared__ float C[4][4][64];     // 4 KB: half-combine
    __shared__ double R[3 * 256];     // 6 KB: final reduction
    __shared__ bool isLast;

    const int t    = threadIdx.x;
    const int lane = t & 63;
    const int wave = __builtin_amdgcn_readfirstlane(t >> 6);
    const int grp  = wave >> 1, half = wave & 1;
    const int jx   = blockIdx.x;
    const int j    = jx * 64 + lane;
    const int i0   = blockIdx.y * 8 + grp * 4;       // uniform

    const float* __restrict__ Ap = hyb + (size_t)i0 * HID + half * 200;  // uniform rows
    const float* __restrict__ Bp = hxT8 + (size_t)(half * 25) * 4096 + (size_t)j * 8;
    const float* __restrict__ Wp = W2 + half * 200;

    float acc[4] = {0.f, 0.f, 0.f, 0.f};

#pragma unroll 5
    for (int g = 0; g < 25; g++) {
        const float* __restrict__ bb = Bp + (size_t)g * 4096;
        float4 b0 = *(const float4*)(bb);            // coalesced dwordx4
        float4 b1v = *(const float4*)(bb + 4);
        float4 w0 = *(const float4*)(Wp + 8 * g);    // uniform -> s_load
        float4 w1 = *(const float4*)(Wp + 8 * g + 4);
#pragma unroll
        for (int c = 0; c < 4; c++) {
            const float* __restrict__ ap = Ap + (size_t)c * HID + 8 * g;  // uniform
            float4 a0 = *(const float4*)(ap);
            float4 a1 = *(const float4*)(ap + 4);
            acc[c] = fmaf(fmaxf(a0.x + b0.x, 0.f), w0.x, acc[c]);
            acc[c] = fmaf(fmaxf(a0.y + b0.y, 0.f), w0.y, acc[c]);
            acc[c] = fmaf(fmaxf(a0.z + b0.z, 0.f), w0.z, acc[c]);
            acc[c] = fmaf(fmaxf(a0.w + b0.w, 0.f), w0.w, acc[c]);
            acc[c] = fmaf(fmaxf(a1.x + b1v.x, 0.f), w1.x, acc[c]);
            acc[c] = fmaf(fmaxf(a1.y + b1v.y, 0.f), w1.y, acc[c]);
            acc[c] = fmaf(fmaxf(a1.z + b1v.z, 0.f), w1.z, acc[c]);
            acc[c] = fmaf(fmaxf(a1.w + b1v.w, 0.f), w1.w, acc[c]);
        }
    }

    // combine the two h-halves of each (grp) via LDS
#pragma unroll
    for (int c = 0; c < 4; c++) C[wave][c][lane] = acc[c];
    __syncthreads();

    if (half == 0) {
        const float bb2 = b2[0];
#pragma unroll
        for (int c = 0; c < 4; c++) {
            const int i = i0 + c;
            float s  = C[wave][c][lane] + C[wave + 1][c][lane] + bb2;
            float es = expf(s);
            float T  = log1pf(es);               // softplus
            if (j == i) diagT[i] = (double)T;    // T0[i]
            double eD = 1.0 + (double)es;        // exp(softplus(s)) exactly
            double tD = (double)T;
            for (int off = 32; off > 0; off >>= 1) {
                eD += __shfl_down(eD, off);
                tD += __shfl_down(tD, off);
            }
            if (lane == 0) {
                expsum[i * 8 + jx] = eD;
                tsum  [i * 8 + jx] = tD;
            }
        }
    }

    // ---- last-block final reduction ----
    __threadfence();
    __syncthreads();
    if (t == 0) isLast = (atomicAdd(counter, 1u) == 511u);
    __syncthreads();
    if (!isLast) return;
    __threadfence();

    double lse = 0.0, tsm = 0.0, dg = 0.0;
    for (int i = t; i < NSAMP; i += 256) {
        double es = 0.0, ts = 0.0;
#pragma unroll
        for (int bq = 0; bq < 8; bq++) { es += expsum[i * 8 + bq]; ts += tsum[i * 8 + bq]; }
        lse += log(es);
        tsm += ts;
        dg  += diagT[i];
    }
    R[t] = lse; R[256 + t] = tsm; R[512 + t] = dg;
    __syncthreads();
    for (int off = 128; off > 0; off >>= 1) {
        if (t < off) {
            R[t]       += R[t + off];
            R[256 + t] += R[256 + t + off];
            R[512 + t] += R[512 + t + off];
        }
        __syncthreads();
    }
    if (t == 0) {
        double t0m  = R[512] / 512.0;
        double lsem = R[0]   / 512.0;
        double t1m  = R[256] / (512.0 * 512.0);
        out[0] = (float)(t0m - (lsem - log(512.0)));   // lower bound
        out[1] = (float)(t0m - t1m);                   // upper bound
    }
}

extern "C" void kernel_launch(void* const* d_in, const int* in_sizes, int n_in,
                              void* d_out, int out_size, void* d_ws, size_t ws_size,
                              hipStream_t stream) {
    const float* X  = (const float*)d_in[0];
    const float* Y  = (const float*)d_in[1];
    const float* W1 = (const float*)d_in[2];
    const float* b1 = (const float*)d_in[3];
    const float* W2 = (const float*)d_in[4];
    const float* b2 = (const float*)d_in[5];
    float* out = (float*)d_out;

    char* ws = (char*)d_ws;
    float*        hxT8    = (float*) (ws);              // 50*512*8*4 = 819200
    float*        hyb     = (float*) (ws +  819200);    // 512*400*4  = 819200
    double*       expsum  = (double*)(ws + 1638400);    // 512*8*8    = 32768
    double*       tsum    = (double*)(ws + 1671168);    // 32768
    double*       diagT   = (double*)(ws + 1703936);    // 4096
    unsigned int* counter = (unsigned int*)(ws + 1708032);

    club_gemm_kernel<<<dim3(848),   256, 0, stream>>>(X, Y, W1, b1, hxT8, hyb, counter);
    club_pair_kernel<<<dim3(8, 64), 256, 0, stream>>>(hxT8, hyb, W2, b2,
                                                      expsum, tsum, diagT, counter, out);
}

// Round 9
// 136.014 us; speedup vs baseline: 1.1030x; 1.1030x over previous
//
#include <hip/hip_runtime.h>
#include <math.h>

// CLUB_NCE: N=512, D=400, H=400.  Two dispatches.
// RULE (R8 lesson): no s_load streams in hot loops — vector memory (vmcnt)
// and ds_read (lgkm, ds-only) pipeline; scalar loads force lgkmcnt(0) drains.
// K1 : hidden GEMMs, 224 blocks x 256 thr, 64n x 64h x 200k (k-split 2).
//      Both operands LDS in [k][row] layout; a-frag broadcast b128, b-frag
//      2-way b128; 4x4 register tile; pure ds+vector pipeline.
//      mat0 -> hxT8_kh[h/8][j][h%8] (oct), mat1 -> hyb_kh[n][h] (b1 in kh0).
// K2 : pair scores, 1024 blocks x 128 thr (2 waves: h-halves). A-rows+W2
//      staged in LDS (broadcast b128 reads); B = 4 coalesced dwordx4 from the
//      two oct partials; fused softplus + per-row fp64 reduce; last-block
//      (atomic counter, validated in R8) does the fp64 logsumexp finish.

#define NSAMP 512
#define DIM 400
#define HID 400

// ---------------- K1 ----------------
// b: mat = b&1, kh = (b>>1)&1, r2 = b>>2: nt = r2&7 (8 n-tiles), ht = r2>>3 (7 h-tiles)
__global__ __launch_bounds__(256) void club_gemm_kernel(
    const float* __restrict__ X, const float* __restrict__ Y,
    const float* __restrict__ W1, const float* __restrict__ b1,
    float* __restrict__ hxT8_0, float* __restrict__ hxT8_1,
    float* __restrict__ hyb0, float* __restrict__ hyb1,
    unsigned int* __restrict__ counter)
{
    __shared__ __align__(16) float As[100 * 64];   // [k][n] 25.6 KB
    __shared__ __align__(16) float Bs[100 * 64];   // [k][h] 25.6 KB
    const int t  = threadIdx.x;
    const int tx = t & 15;          // h-quad
    const int ty = t >> 4;          // n-quad
    const int b  = blockIdx.x;
    if (b == 0 && t == 0) *counter = 0u;

    const int mat = b & 1, kh = (b >> 1) & 1, r2 = b >> 2;
    const int n0 = (r2 & 7) * 64, h0 = (r2 >> 3) * 64;
    const float* __restrict__ src = mat ? Y : X;   // A rows [512][400]
    const int wcol  = mat ? DIM : 0;
    const int kbase = kh * 200;

    float acc[4][4];                // [c(h)][r(n)]
#pragma unroll
    for (int c = 0; c < 4; c++)
#pragma unroll
        for (int r = 0; r < 4; r++) acc[c][r] = 0.f;

    for (int kc = 0; kc < 200; kc += 100) {
        __syncthreads();
        // stage A: X/Y rows n0..n0+63, k-chunk -> As[k][n]. lane-consecutive n
        // => conflict-free b32 LDS writes; global reads scattered (L2-served).
        for (int idx = t; idx < 1600; idx += 256) {
            const int n = idx & 63, kq = idx >> 6;
            float4 v = *(const float4*)(src + (size_t)(n0 + n) * DIM + kbase + kc + 4 * kq);
            float* d = As + (4 * kq) * 64 + n;
            d[0] = v.x; d[64] = v.y; d[128] = v.z; d[192] = v.w;
        }
        // stage B: W1 rows h0..h0+63 (clamped), cols wcol+k -> Bs[k][h]
        for (int idx = t; idx < 1600; idx += 256) {
            const int h = idx & 63, kq = idx >> 6;
            int hr = h0 + h; if (hr > HID - 1) hr = HID - 1;
            float4 v = *(const float4*)(W1 + (size_t)hr * (2 * DIM) + wcol + kbase + kc + 4 * kq);
            float* d = Bs + (4 * kq) * 64 + h;
            d[0] = v.x; d[64] = v.y; d[128] = v.z; d[192] = v.w;
        }
        __syncthreads();
#pragma unroll 4
        for (int k = 0; k < 100; k++) {
            float4 av = *(const float4*)(As + k * 64 + 4 * ty);   // broadcast b128
            float4 bv = *(const float4*)(Bs + k * 64 + 4 * tx);   // 2-way b128
            acc[0][0] = fmaf(av.x, bv.x, acc[0][0]);
            acc[0][1] = fmaf(av.y, bv.x, acc[0][1]);
            acc[0][2] = fmaf(av.z, bv.x, acc[0][2]);
            acc[0][3] = fmaf(av.w, bv.x, acc[0][3]);
            acc[1][0] = fmaf(av.x, bv.y, acc[1][0]);
            acc[1][1] = fmaf(av.y, bv.y, acc[1][1]);
            acc[1][2] = fmaf(av.z, bv.y, acc[1][2]);
            acc[1][3] = fmaf(av.w, bv.y, acc[1][3]);
            acc[2][0] = fmaf(av.x, bv.z, acc[2][0]);
            acc[2][1] = fmaf(av.y, bv.z, acc[2][1]);
            acc[2][2] = fmaf(av.z, bv.z, acc[2][2]);
            acc[2][3] = fmaf(av.w, bv.z, acc[2][3]);
            acc[3][0] = fmaf(av.x, bv.w, acc[3][0]);
            acc[3][1] = fmaf(av.y, bv.w, acc[3][1]);
            acc[3][2] = fmaf(av.z, bv.w, acc[3][2]);
            acc[3][3] = fmaf(av.w, bv.w, acc[3][3]);
        }
    }

    const int hq = h0 + 4 * tx;
    if (hq < HID) {
        if (mat == 0) {
            // oct store: hxT8[g][j][o], g = hq>>3, o = hq&7 (0 or 4)
            float* __restrict__ dst = kh ? hxT8_1 : hxT8_0;
            const int g = hq >> 3, o = hq & 7;
#pragma unroll
            for (int r = 0; r < 4; r++) {
                const int j = n0 + 4 * ty + r;
                *(float4*)(dst + ((size_t)g * NSAMP + j) * 8 + o) =
                    make_float4(acc[0][r], acc[1][r], acc[2][r], acc[3][r]);
            }
        } else {
            float* __restrict__ dst = kh ? hyb1 : hyb0;
            if (kh == 0) {
                float4 bv = *(const float4*)(b1 + hq);
#pragma unroll
                for (int r = 0; r < 4; r++) {
                    acc[0][r] += bv.x; acc[1][r] += bv.y;
                    acc[2][r] += bv.z; acc[3][r] += bv.w;
                }
            }
#pragma unroll
            for (int r = 0; r < 4; r++) {
                const int n = n0 + 4 * ty + r;
                *(float4*)(dst + (size_t)n * HID + hq) =
                    make_float4(acc[0][r], acc[1][r], acc[2][r], acc[3][r]);
            }
        }
    }
}

// ---------------- K2: pair scores + fused final ----------------
// grid (8 jx, 128 ig), block 128 (2 waves = 2 h-halves). wave: 4 i x 64 j x 200 h.
__global__ __launch_bounds__(128) void club_pair_kernel(
    const float* __restrict__ hxT8_0, const float* __restrict__ hxT8_1,
    const float* __restrict__ hyb0, const float* __restrict__ hyb1,
    const float* __restrict__ W2, const float* __restrict__ b2,
    double* __restrict__ expsum, double* __restrict__ tsum,
    double* __restrict__ diagT, unsigned int* __restrict__ counter,
    float* __restrict__ out)
{
    __shared__ __align__(16) float As4[4 * 400];   // combined hyb rows i0..i0+3
    __shared__ __align__(16) float W2s[400];
    __shared__ float Cs[4][64];                    // half-1 partial accs
    __shared__ double Rs[3 * 128];
    __shared__ bool isLast;

    const int t    = threadIdx.x;
    const int lane = t & 63;
    const int half = __builtin_amdgcn_readfirstlane(t >> 6);   // 0 or 1
    const int jx   = blockIdx.x;
    const int ig   = blockIdx.y;
    const int i0   = ig * 4;
    const int j    = jx * 64 + lane;

    // stage A (hyb0+hyb1; b1 already folded) and W2 into LDS
    for (int idx = t; idx < 400; idx += 128) {
        const int il = idx / 100, q = idx % 100;
        const size_t off = (size_t)(i0 + il) * HID + 4 * q;
        float4 v0 = *(const float4*)(hyb0 + off);
        float4 v1 = *(const float4*)(hyb1 + off);
        *(float4*)(As4 + il * 400 + 4 * q) =
            make_float4(v0.x + v1.x, v0.y + v1.y, v0.z + v1.z, v0.w + v1.w);
    }
    if (t < 100) *(float4*)(W2s + 4 * t) = *(const float4*)(W2 + 4 * t);
    __syncthreads();

    const float* __restrict__ Bp0 = hxT8_0 + ((size_t)(half * 25) * NSAMP + j) * 8;
    const float* __restrict__ Bp1 = hxT8_1 + ((size_t)(half * 25) * NSAMP + j) * 8;
    const int hbase = half * 200;

    float acc[4] = {0.f, 0.f, 0.f, 0.f};

#pragma unroll 5
    for (int g = 0; g < 25; g++) {
        const size_t go = (size_t)g * 4096;
        float4 p0 = *(const float4*)(Bp0 + go);        // coalesced dwordx4
        float4 p1 = *(const float4*)(Bp0 + go + 4);
        float4 q0 = *(const float4*)(Bp1 + go);
        float4 q1 = *(const float4*)(Bp1 + go + 4);
        float4 B0 = make_float4(p0.x + q0.x, p0.y + q0.y, p0.z + q0.z, p0.w + q0.w);
        float4 B1 = make_float4(p1.x + q1.x, p1.y + q1.y, p1.z + q1.z, p1.w + q1.w);
        float4 w0 = *(const float4*)(W2s + hbase + 8 * g);      // broadcast b128
        float4 w1 = *(const float4*)(W2s + hbase + 8 * g + 4);
#pragma unroll
        for (int il = 0; il < 4; il++) {
            const float* __restrict__ ap = As4 + il * 400 + hbase + 8 * g;
            float4 a0 = *(const float4*)(ap);                   // broadcast b128
            float4 a1 = *(const float4*)(ap + 4);
            acc[il] = fmaf(fmaxf(a0.x + B0.x, 0.f), w0.x, acc[il]);
            acc[il] = fmaf(fmaxf(a0.y + B0.y, 0.f), w0.y, acc[il]);
            acc[il] = fmaf(fmaxf(a0.z + B0.z, 0.f), w0.z, acc[il]);
            acc[il] = fmaf(fmaxf(a0.w + B0.w, 0.f), w0.w, acc[il]);
            acc[il] = fmaf(fmaxf(a1.x + B1.x, 0.f), w1.x, acc[il]);
            acc[il] = fmaf(fmaxf(a1.y + B1.y, 0.f), w1.y, acc[il]);
            acc[il] = fmaf(fmaxf(a1.z + B1.z, 0.f), w1.z, acc[il]);
            acc[il] = fmaf(fmaxf(a1.w + B1.w, 0.f), w1.w, acc[il]);
        }
    }

    // combine the two h-halves via LDS
    if (half == 1) {
#pragma unroll
        for (int il = 0; il < 4; il++) Cs[il][lane] = acc[il];
    }
    __syncthreads();

    if (half == 0) {
        const float bb2 = b2[0];
#pragma unroll
        for (int il = 0; il < 4; il++) {
            const int i = i0 + il;
            float s  = acc[il] + Cs[il][lane] + bb2;
            float es = expf(s);
            float T  = log1pf(es);               // softplus
            if (j == i) diagT[i] = (double)T;    // T0[i]
            double eD = 1.0 + (double)es;        // exp(softplus(s)) exactly
            double tD = (double)T;
            for (int off = 32; off > 0; off >>= 1) {
                eD += __shfl_down(eD, off);
                tD += __shfl_down(tD, off);
            }
            if (lane == 0) {
                expsum[i * 8 + jx] = eD;
                tsum  [i * 8 + jx] = tD;
            }
        }
    }

    // ---- last-block final reduction (pattern validated in R8) ----
    __threadfence();
    __syncthreads();
    if (t == 0) isLast = (atomicAdd(counter, 1u) == 1023u);
    __syncthreads();
    if (!isLast) return;
    __threadfence();

    double lse = 0.0, tsm = 0.0, dg = 0.0;
    for (int i = t; i < NSAMP; i += 128) {
        double es = 0.0, ts = 0.0;
#pragma unroll
        for (int bq = 0; bq < 8; bq++) { es += expsum[i * 8 + bq]; ts += tsum[i * 8 + bq]; }
        lse += log(es);
        tsm += ts;
        dg  += diagT[i];
    }
    Rs[t] = lse; Rs[128 + t] = tsm; Rs[256 + t] = dg;
    __syncthreads();
    for (int off = 64; off > 0; off >>= 1) {
        if (t < off) {
            Rs[t]       += Rs[t + off];
            Rs[128 + t] += Rs[128 + t + off];
            Rs[256 + t] += Rs[256 + t + off];
        }
        __syncthreads();
    }
    if (t == 0) {
        double t0m  = Rs[256] / 512.0;
        double lsem = Rs[0]   / 512.0;
        double t1m  = Rs[128] / (512.0 * 512.0);
        out[0] = (float)(t0m - (lsem - log(512.0)));   // lower bound
        out[1] = (float)(t0m - t1m);                   // upper bound
    }
}

extern "C" void kernel_launch(void* const* d_in, const int* in_sizes, int n_in,
                              void* d_out, int out_size, void* d_ws, size_t ws_size,
                              hipStream_t stream) {
    const float* X  = (const float*)d_in[0];
    const float* Y  = (const float*)d_in[1];
    const float* W1 = (const float*)d_in[2];
    const float* b1 = (const float*)d_in[3];
    const float* W2 = (const float*)d_in[4];
    const float* b2 = (const float*)d_in[5];
    float* out = (float*)d_out;

    char* ws = (char*)d_ws;
    float*        hxT8_0  = (float*) (ws);               // 50*512*8*4 = 819200
    float*        hxT8_1  = (float*) (ws +  819200);
    float*        hyb0    = (float*) (ws + 1638400);     // 512*400*4
    float*        hyb1    = (float*) (ws + 2457600);
    double*       expsum  = (double*)(ws + 3276800);     // 512*8*8 = 32768
    double*       tsum    = (double*)(ws + 3309568);     // 32768
    double*       diagT   = (double*)(ws + 3342336);     // 4096
    unsigned int* counter = (unsigned int*)(ws + 3346432);

    club_gemm_kernel<<<dim3(224),    256, 0, stream>>>(X, Y, W1, b1,
                                                       hxT8_0, hxT8_1, hyb0, hyb1, counter);
    club_pair_kernel<<<dim3(8, 128), 128, 0, stream>>>(hxT8_0, hxT8_1, hyb0, hyb1,
                                                       W2, b2, expsum, tsum, diagT,
                                                       counter, out);
}